// Round 1
// baseline (64.200 us; speedup 1.0000x reference)
//
#include <hip/hip_runtime.h>

// MedianBlur 3x3 + residual: out = x + 0.2*(median3x3(x, zero-pad) - x)
// x: [8, 64, 256, 256] fp32. Rows are 256 floats; every (b,c,h) row is an
// independent "global row" gr in [0, 8*64*256). Vertical neighbors only valid
// within the same image: y = gr & 255.

typedef float f4 __attribute__((ext_vector_type(4)));

__device__ __forceinline__ float min3f(float a, float b, float c) { return fminf(fminf(a, b), c); }
__device__ __forceinline__ float max3f(float a, float b, float c) { return fmaxf(fmaxf(a, b), c); }
__device__ __forceinline__ float med3f(float a, float b, float c) { return __builtin_amdgcn_fmed3f(a, b, c); }

__global__ __launch_bounds__(256) void median_blur_k(const float* __restrict__ x,
                                                     float* __restrict__ out) {
    const int tid = threadIdx.x;
    // 4 rows per block; each wave (64 lanes) owns one full row -> y is
    // wave-uniform, row-validity branches are scalar branches.
    const int gr  = (blockIdx.x << 2) + (tid >> 6);   // global row index
    const int y   = gr & 255;                         // row within image
    const int x4  = (tid & 63) << 2;                  // first of 4 columns
    const size_t base = ((size_t)gr << 8) + (size_t)x4;
    const float* rc = x + base;

    const bool hasL = (x4 > 0);
    const bool hasR = (x4 < 252);
    const int  li   = hasL ? -1 : 0;   // clamped: load stays in-bounds, select 0 after
    const int  ri   = hasR ?  4 : 0;

    // middle row: aligned float4 + 2 edge scalars
    f4 vm = *(const f4*)rc;
    float lm = rc[li]; lm = hasL ? lm : 0.0f;
    float rm = rc[ri]; rm = hasR ? rm : 0.0f;

    // row above (zero if y==0) — wave-uniform branch
    f4 vu = {0.f, 0.f, 0.f, 0.f}; float lu = 0.f, ru = 0.f;
    if (y > 0) {
        const float* rp = rc - 256;
        vu = *(const f4*)rp;
        float t0 = rp[li]; lu = hasL ? t0 : 0.0f;
        float t1 = rp[ri]; ru = hasR ? t1 : 0.0f;
    }
    // row below (zero if y==255)
    f4 vd = {0.f, 0.f, 0.f, 0.f}; float ld = 0.f, rd = 0.f;
    if (y < 255) {
        const float* rp = rc + 256;
        vd = *(const f4*)rp;
        float t0 = rp[li]; ld = hasL ? t0 : 0.0f;
        float t1 = rp[ri]; rd = hasR ? t1 : 0.0f;
    }

    // 6 columns cover the 4 output pixels' 3x3 windows.
    // Sort each column of 3 (min3/med3/max3 -> v_min3/med3/max3_f32),
    // then exact identity: median9 = med3(max3(mins), med3(mids), min3(maxes)).
    float cu[6] = {lu, vu.x, vu.y, vu.z, vu.w, ru};
    float cm[6] = {lm, vm.x, vm.y, vm.z, vm.w, rm};
    float cd[6] = {ld, vd.x, vd.y, vd.z, vd.w, rd};
    float lo[6], mi[6], hi[6];
#pragma unroll
    for (int k = 0; k < 6; ++k) {
        lo[k] = min3f(cu[k], cm[k], cd[k]);
        mi[k] = med3f(cu[k], cm[k], cd[k]);
        hi[k] = max3f(cu[k], cm[k], cd[k]);
    }

    f4 o;
#pragma unroll
    for (int j = 0; j < 4; ++j) {
        float L = max3f(lo[j], lo[j + 1], lo[j + 2]);
        float M = med3f(mi[j], mi[j + 1], mi[j + 2]);
        float U = min3f(hi[j], hi[j + 1], hi[j + 2]);
        float med = med3f(L, M, U);
        float xv  = vm[j];
        o[j] = xv + 0.2f * (med - xv);   // same fp32 expression as reference
    }
    *(f4*)(out + base) = o;
}

extern "C" void kernel_launch(void* const* d_in, const int* in_sizes, int n_in,
                              void* d_out, int out_size, void* d_ws, size_t ws_size,
                              hipStream_t stream) {
    const float* xin = (const float*)d_in[0];
    float* out = (float*)d_out;
    const int total_rows = out_size >> 8;   // B*C*H = 131072 rows of 256
    const int blocks = total_rows >> 2;     // 4 rows (one per wave) per block
    median_blur_k<<<blocks, 256, 0, stream>>>(xin, out);
}

// Round 2
// 45.663 us; speedup vs baseline: 1.4060x; 1.4060x over previous
//
#include <hip/hip_runtime.h>

// MedianBlur 3x3 + residual, x: [8,64,256,256] fp32, zero padding.
// R2: vertical register blocking — each wave (64 lanes) computes 4 consecutive
// output rows of one image; lane owns columns 4*lane..4*lane+3. Loads 6 input
// rows as float4 (1.5x L1 read amp vs 4.5x in R1), horizontal neighbors via
// cross-lane shuffles (no extra loads), nontemporal output stores.

typedef float f4 __attribute__((ext_vector_type(4)));

__device__ __forceinline__ float min3f(float a, float b, float c) { return fminf(fminf(a, b), c); }
__device__ __forceinline__ float max3f(float a, float b, float c) { return fmaxf(fmaxf(a, b), c); }
__device__ __forceinline__ float med3f(float a, float b, float c) { return __builtin_amdgcn_fmed3f(a, b, c); }

__global__ __launch_bounds__(256) void median_blur_k(const float* __restrict__ x,
                                                     float* __restrict__ out) {
    const int tid  = threadIdx.x;
    const int lane = tid & 63;
    const int wave = tid >> 6;
    // each wave handles a group of 4 consecutive rows; 4 waves/block -> 16 rows
    const int grp = (blockIdx.x << 2) + wave;
    const int gr0 = grp << 2;            // first global row of group
    const int y0  = gr0 & 255;           // row within image: 0,4,...,252
    const size_t base = ((size_t)gr0 << 8) + ((size_t)lane << 2);
    const float* p = x + base;

    // rows y0-1 .. y0+4 (zero rows outside the image; branches wave-uniform)
    f4 in[6];
    const f4 z = {0.f, 0.f, 0.f, 0.f};
    in[0] = (y0 > 0)   ? *(const f4*)(p - 256)  : z;
    in[1] = *(const f4*)(p);
    in[2] = *(const f4*)(p + 256);
    in[3] = *(const f4*)(p + 512);
    in[4] = *(const f4*)(p + 768);
    in[5] = (y0 < 252) ? *(const f4*)(p + 1024) : z;

    // horizontal neighbors from adjacent lanes (zero at image edges)
    const bool hasL = (lane > 0);
    const bool hasR = (lane < 63);
    float L[6], R[6];
#pragma unroll
    for (int r = 0; r < 6; ++r) {
        float lv = __shfl(in[r].w, lane - 1, 64);
        float rv = __shfl(in[r].x, lane + 1, 64);
        L[r] = hasL ? lv : 0.0f;
        R[r] = hasR ? rv : 0.0f;
    }

#pragma unroll
    for (int k = 0; k < 4; ++k) {
        // column triple rows: in[k], in[k+1], in[k+2]; 6 columns (-1..4)
        float cu[6] = {L[k],   in[k].x,   in[k].y,   in[k].z,   in[k].w,   R[k]};
        float cm[6] = {L[k+1], in[k+1].x, in[k+1].y, in[k+1].z, in[k+1].w, R[k+1]};
        float cd[6] = {L[k+2], in[k+2].x, in[k+2].y, in[k+2].z, in[k+2].w, R[k+2]};
        float lo[6], mi[6], hi[6];
#pragma unroll
        for (int j = 0; j < 6; ++j) {
            lo[j] = min3f(cu[j], cm[j], cd[j]);   // v_min3_f32
            mi[j] = med3f(cu[j], cm[j], cd[j]);   // v_med3_f32
            hi[j] = max3f(cu[j], cm[j], cd[j]);   // v_max3_f32
        }
        f4 o;
#pragma unroll
        for (int j = 0; j < 4; ++j) {
            float Lm = max3f(lo[j], lo[j + 1], lo[j + 2]);
            float Mm = med3f(mi[j], mi[j + 1], mi[j + 2]);
            float Um = min3f(hi[j], hi[j + 1], hi[j + 2]);
            float med = med3f(Lm, Mm, Um);
            float xv  = cm[j + 1];               // center pixel = in[k+1][j]
            o[j] = xv + 0.2f * (med - xv);
        }
        __builtin_nontemporal_store(o, (f4*)(out + base + (size_t)(k << 8)));
    }
}

extern "C" void kernel_launch(void* const* d_in, const int* in_sizes, int n_in,
                              void* d_out, int out_size, void* d_ws, size_t ws_size,
                              hipStream_t stream) {
    const float* xin = (const float*)d_in[0];
    float* out = (float*)d_out;
    const int total_rows = out_size >> 8;     // 131072 rows of 256 floats
    const int groups = total_rows >> 2;       // 4-row groups (one per wave)
    const int blocks = groups >> 2;           // 4 waves per block
    median_blur_k<<<blocks, 256, 0, stream>>>(xin, out);
}

// Round 3
// 44.984 us; speedup vs baseline: 1.4272x; 1.0151x over previous
//
#include <hip/hip_runtime.h>

// MedianBlur 3x3 + residual, x: [8,64,256,256] fp32, zero padding.
// R3: 8-row vertical register blocking per wave (10 row loads per 8 output
// rows -> 1.25x L1 read amp vs 1.5x in R2). Lane owns columns 4l..4l+3;
// horizontal neighbors via cross-lane shuffles; nontemporal f4 stores.

typedef float f4 __attribute__((ext_vector_type(4)));

__device__ __forceinline__ float min3f(float a, float b, float c) { return fminf(fminf(a, b), c); }
__device__ __forceinline__ float max3f(float a, float b, float c) { return fmaxf(fmaxf(a, b), c); }
__device__ __forceinline__ float med3f(float a, float b, float c) { return __builtin_amdgcn_fmed3f(a, b, c); }

__global__ __launch_bounds__(256) void median_blur_k(const float* __restrict__ x,
                                                     float* __restrict__ out) {
    const int tid  = threadIdx.x;
    const int lane = tid & 63;
    const int wave = tid >> 6;
    // each wave handles 8 consecutive rows of one image; 4 waves/block
    const int grp = (blockIdx.x << 2) + wave;
    const int gr0 = grp << 3;            // first global row of group
    const int y0  = gr0 & 255;           // row within image: 0,8,...,248
    const size_t base = ((size_t)gr0 << 8) + ((size_t)lane << 2);
    const float* p = x + base;

    // rows y0-1 .. y0+8 (zero rows outside the image; branches wave-uniform)
    f4 in[10];
    const f4 z = {0.f, 0.f, 0.f, 0.f};
    in[0] = (y0 > 0) ? *(const f4*)(p - 256) : z;
#pragma unroll
    for (int i = 1; i <= 8; ++i)
        in[i] = *(const f4*)(p + (size_t)((i - 1) << 8));
    in[9] = (y0 < 248) ? *(const f4*)(p + (size_t)(8 << 8)) : z;

    // horizontal neighbors from adjacent lanes (zero at image edges)
    const bool hasL = (lane > 0);
    const bool hasR = (lane < 63);
    float L[10], R[10];
#pragma unroll
    for (int r = 0; r < 10; ++r) {
        float lv = __shfl(in[r].w, lane - 1, 64);
        float rv = __shfl(in[r].x, lane + 1, 64);
        L[r] = hasL ? lv : 0.0f;
        R[r] = hasR ? rv : 0.0f;
    }

#pragma unroll
    for (int k = 0; k < 8; ++k) {
        // column triple rows: in[k], in[k+1], in[k+2]; 6 columns (-1..4)
        float cu[6] = {L[k],   in[k].x,   in[k].y,   in[k].z,   in[k].w,   R[k]};
        float cm[6] = {L[k+1], in[k+1].x, in[k+1].y, in[k+1].z, in[k+1].w, R[k+1]};
        float cd[6] = {L[k+2], in[k+2].x, in[k+2].y, in[k+2].z, in[k+2].w, R[k+2]};
        float lo[6], mi[6], hi[6];
#pragma unroll
        for (int j = 0; j < 6; ++j) {
            lo[j] = min3f(cu[j], cm[j], cd[j]);   // v_min3_f32
            mi[j] = med3f(cu[j], cm[j], cd[j]);   // v_med3_f32
            hi[j] = max3f(cu[j], cm[j], cd[j]);   // v_max3_f32
        }
        f4 o;
#pragma unroll
        for (int j = 0; j < 4; ++j) {
            float Lm = max3f(lo[j], lo[j + 1], lo[j + 2]);
            float Mm = med3f(mi[j], mi[j + 1], mi[j + 2]);
            float Um = min3f(hi[j], hi[j + 1], hi[j + 2]);
            float med = med3f(Lm, Mm, Um);
            float xv  = cm[j + 1];               // center pixel
            o[j] = xv + 0.2f * (med - xv);
        }
        __builtin_nontemporal_store(o, (f4*)(out + base + (size_t)(k << 8)));
    }
}

extern "C" void kernel_launch(void* const* d_in, const int* in_sizes, int n_in,
                              void* d_out, int out_size, void* d_ws, size_t ws_size,
                              hipStream_t stream) {
    const float* xin = (const float*)d_in[0];
    float* out = (float*)d_out;
    const int total_rows = out_size >> 8;     // 131072 rows of 256 floats
    const int groups = total_rows >> 3;       // 8-row groups (one per wave)
    const int blocks = groups >> 2;           // 4 waves per block
    median_blur_k<<<blocks, 256, 0, stream>>>(xin, out);
}